// Round 1
// baseline (423.686 us; speedup 1.0000x reference)
//
#include <hip/hip_runtime.h>
#include <math.h>

namespace {
constexpr int kB = 128;
constexpr int kT = 2048;
constexpr int kH = 256;
constexpr int kS = 16;            // chunks per batch (main pass)
constexpr int kTC = kT / kS;      // 128 timesteps per workgroup
}

__device__ __forceinline__ float dot4(float4 a, float4 b) {
    return fmaf(a.x, b.x, fmaf(a.y, b.y, fmaf(a.z, b.z, a.w * b.w)));
}

// ---- Kernel A: v[b,h] = sum_k W_score[h,k] * hidden[b,T-1,k] ----
__global__ __launch_bounds__(256) void compute_v_kernel(
    const float* __restrict__ hs, const float* __restrict__ Wsc,
    float* __restrict__ v) {
    const int b = blockIdx.x;
    const int tid = threadIdx.x;
    __shared__ float sh[kH];
    sh[tid] = hs[(size_t)b * kT * kH + (size_t)(kT - 1) * kH + tid];
    __syncthreads();
    const int wv = tid >> 6, lane = tid & 63;
    const float4 hv = *reinterpret_cast<const float4*>(&sh[lane * 4]);
    for (int r = 0; r < 64; ++r) {
        const int h = wv * 64 + r;
        const float4 wr =
            *reinterpret_cast<const float4*>(&Wsc[(size_t)h * kH + lane * 4]);
        float s = dot4(wr, hv);
        #pragma unroll
        for (int off = 32; off > 0; off >>= 1) s += __shfl_xor(s, off, 64);
        if (lane == 0) v[b * kH + h] = s;
    }
}

// ---- Kernel B: fused score + online softmax + weighted context, one pass ----
// Each wave processes 4 timesteps per iteration; per-wave online softmax
// state (m, l, ctx[256] as float4/lane) merged across 4 waves via LDS;
// per-chunk partials written to workspace.
__global__ __launch_bounds__(256) void main_pass_kernel(
    const float* __restrict__ hs, const float* __restrict__ v,
    float* __restrict__ M, float* __restrict__ L, float* __restrict__ CTX) {
    const int chunk = blockIdx.x;   // 0..kS-1
    const int b = blockIdx.y;       // 0..kB-1
    const int tid = threadIdx.x;
    const int wv = tid >> 6, lane = tid & 63;

    const float4 vv = *reinterpret_cast<const float4*>(&v[b * kH + lane * 4]);
    const float* base = hs + (size_t)b * kT * kH + (size_t)chunk * kTC * kH;

    float m = -INFINITY, l = 0.f;
    float4 acc = make_float4(0.f, 0.f, 0.f, 0.f);

    #pragma unroll 2
    for (int it = 0; it < kTC / 16; ++it) {
        const float* p = base + (size_t)(it * 16 + wv * 4) * kH + lane * 4;
        const float4 x0 = *reinterpret_cast<const float4*>(p);
        const float4 x1 = *reinterpret_cast<const float4*>(p + kH);
        const float4 x2 = *reinterpret_cast<const float4*>(p + 2 * kH);
        const float4 x3 = *reinterpret_cast<const float4*>(p + 3 * kH);
        float s0 = dot4(x0, vv);
        float s1 = dot4(x1, vv);
        float s2 = dot4(x2, vv);
        float s3 = dot4(x3, vv);
        #pragma unroll
        for (int off = 32; off > 0; off >>= 1) {
            s0 += __shfl_xor(s0, off, 64);
            s1 += __shfl_xor(s1, off, 64);
            s2 += __shfl_xor(s2, off, 64);
            s3 += __shfl_xor(s3, off, 64);
        }
        const float nm =
            fmaxf(fmaxf(m, fmaxf(s0, s1)), fmaxf(s2, s3));
        const float scale = __expf(m - nm);
        const float p0 = __expf(s0 - nm);
        const float p1 = __expf(s1 - nm);
        const float p2 = __expf(s2 - nm);
        const float p3 = __expf(s3 - nm);
        l = fmaf(l, scale, (p0 + p1) + (p2 + p3));
        acc.x = fmaf(acc.x, scale,
                     fmaf(p0, x0.x, fmaf(p1, x1.x, fmaf(p2, x2.x, p3 * x3.x))));
        acc.y = fmaf(acc.y, scale,
                     fmaf(p0, x0.y, fmaf(p1, x1.y, fmaf(p2, x2.y, p3 * x3.y))));
        acc.z = fmaf(acc.z, scale,
                     fmaf(p0, x0.z, fmaf(p1, x1.z, fmaf(p2, x2.z, p3 * x3.z))));
        acc.w = fmaf(acc.w, scale,
                     fmaf(p0, x0.w, fmaf(p1, x1.w, fmaf(p2, x2.w, p3 * x3.w))));
        m = nm;
    }

    // Merge the 4 waves' partial softmax states in LDS.
    __shared__ float shm[4];
    __shared__ float shl[4];
    __shared__ float shctx[4 * kH];
    if (lane == 0) { shm[wv] = m; shl[wv] = l; }
    *reinterpret_cast<float4*>(&shctx[wv * kH + lane * 4]) = acc;
    __syncthreads();

    const float m0 = shm[0], m1 = shm[1], m2 = shm[2], m3 = shm[3];
    const float gm = fmaxf(fmaxf(m0, m1), fmaxf(m2, m3));
    const float e0 = __expf(m0 - gm), e1 = __expf(m1 - gm);
    const float e2 = __expf(m2 - gm), e3 = __expf(m3 - gm);

    const int pidx = b * kS + chunk;
    const float ctx = shctx[tid] * e0 + shctx[kH + tid] * e1 +
                      shctx[2 * kH + tid] * e2 + shctx[3 * kH + tid] * e3;
    CTX[(size_t)pidx * kH + tid] = ctx;
    if (tid == 0) {
        M[pidx] = gm;
        L[pidx] = shl[0] * e0 + shl[1] * e1 + shl[2] * e2 + shl[3] * e3;
    }
}

// ---- Kernel C: merge chunk partials, concat with h_t, matvec W_att, tanh ----
__global__ __launch_bounds__(256) void finalize_kernel(
    const float* __restrict__ hs, const float* __restrict__ M,
    const float* __restrict__ L, const float* __restrict__ CTX,
    const float* __restrict__ Watt, float* __restrict__ out) {
    const int b = blockIdx.x;
    const int tid = threadIdx.x;     // 256 threads
    __shared__ float pre[2 * kH];    // [context(256) | h_t(256)]
    __shared__ float red[128];

    // Merge kS partials for h = tid.
    float gm = -INFINITY;
    #pragma unroll
    for (int c = 0; c < kS; ++c) gm = fmaxf(gm, M[b * kS + c]);
    float gl = 0.f, ctx = 0.f;
    #pragma unroll
    for (int c = 0; c < kS; ++c) {
        const float e = __expf(M[b * kS + c] - gm);
        gl = fmaf(L[b * kS + c], e, gl);
        ctx = fmaf(CTX[(size_t)(b * kS + c) * kH + tid], e, ctx);
    }
    pre[tid] = ctx / gl;
    pre[kH + tid] = hs[(size_t)b * kT * kH + (size_t)(kT - 1) * kH + tid];
    __syncthreads();

    // out[b,j] = tanh(sum_i pre[i] * Watt[i,j]); split i-range across halves.
    const int j = tid & 127, half = tid >> 7;
    float s = 0.f;
    const int i0 = half * 256;
    #pragma unroll 4
    for (int i = i0; i < i0 + 256; ++i)
        s = fmaf(pre[i], Watt[(size_t)i * 128 + j], s);
    if (half == 1) red[j] = s;
    __syncthreads();
    if (half == 0) out[b * 128 + j] = tanhf(s + red[j]);
}

extern "C" void kernel_launch(void* const* d_in, const int* in_sizes, int n_in,
                              void* d_out, int out_size, void* d_ws, size_t ws_size,
                              hipStream_t stream) {
    const float* hs   = (const float*)d_in[0];   // (B, T, H) fp32
    const float* Wsc  = (const float*)d_in[1];   // (H, H) fp32
    const float* Watt = (const float*)d_in[2];   // (2H, 128) fp32
    float* out = (float*)d_out;                  // (B, 128) fp32

    float* ws  = (float*)d_ws;
    float* v   = ws;                 // kB*kH        = 32768 floats
    float* M   = v + kB * kH;        // kB*kS        = 2048
    float* L   = M + kB * kS;        // kB*kS        = 2048
    float* CTX = L + kB * kS;        // kB*kS*kH     = 524288 floats

    compute_v_kernel<<<kB, 256, 0, stream>>>(hs, Wsc, v);
    main_pass_kernel<<<dim3(kS, kB), 256, 0, stream>>>(hs, v, M, L, CTX);
    finalize_kernel<<<kB, 256, 0, stream>>>(hs, M, L, CTX, Watt, out);
}

// Round 2
// 399.534 us; speedup vs baseline: 1.0605x; 1.0605x over previous
//
#include <hip/hip_runtime.h>
#include <math.h>

namespace {
constexpr int kB = 128;
constexpr int kT = 2048;
constexpr int kH = 256;
constexpr int kS = 16;            // chunks per batch (main pass)
constexpr int kTC = kT / kS;      // 128 timesteps per workgroup
}

__device__ __forceinline__ float dot4(float4 a, float4 b) {
    return fmaf(a.x, b.x, fmaf(a.y, b.y, fmaf(a.z, b.z, a.w * b.w)));
}

// DPP-based full-wave64 sum reduction (canonical gfx9 sequence, no LDS/DS ops).
// Result returned as a wave-uniform value (via readlane 63 -> SGPR).
template <int CTRL, int ROW_MASK>
__device__ __forceinline__ float dpp_add(float x) {
    int n = __builtin_amdgcn_update_dpp(0, __float_as_int(x), CTRL, ROW_MASK,
                                        0xf, true);
    return x + __int_as_float(n);
}

__device__ __forceinline__ float wave_sum(float x) {
    x = dpp_add<0xB1, 0xf>(x);    // quad_perm [1,0,3,2]  : xor1
    x = dpp_add<0x4E, 0xf>(x);    // quad_perm [2,3,0,1]  : xor2
    x = dpp_add<0x141, 0xf>(x);   // row_half_mirror      : xor4-equiv
    x = dpp_add<0x140, 0xf>(x);   // row_mirror           : xor8-equiv
    x = dpp_add<0x142, 0xa>(x);   // row_bcast15 -> rows 1,3
    x = dpp_add<0x143, 0xc>(x);   // row_bcast31 -> rows 2,3
    return __int_as_float(__builtin_amdgcn_readlane(__float_as_int(x), 63));
}

// ---- Kernel A: v[b,h] = sum_k W_score[h,k] * hidden[b,T-1,k] ----
__global__ __launch_bounds__(256) void compute_v_kernel(
    const float* __restrict__ hs, const float* __restrict__ Wsc,
    float* __restrict__ v) {
    const int half = blockIdx.x;     // 0..1
    const int b = blockIdx.y;
    const int tid = threadIdx.x;
    __shared__ float sh[kH];
    sh[tid] = hs[(size_t)b * kT * kH + (size_t)(kT - 1) * kH + tid];
    __syncthreads();
    const int wv = tid >> 6, lane = tid & 63;
    const float4 hv = *reinterpret_cast<const float4*>(&sh[lane * 4]);
    #pragma unroll 4
    for (int r = 0; r < 32; ++r) {
        const int h = half * 128 + wv * 32 + r;
        const float4 wr =
            *reinterpret_cast<const float4*>(&Wsc[(size_t)h * kH + lane * 4]);
        const float s = wave_sum(dot4(wr, hv));
        if (lane == 0) v[b * kH + h] = s;
    }
}

// ---- Kernel B: fused score + online softmax + weighted context, one pass ----
// Each wave: 8 timesteps/iteration, DPP reductions (no DS ops), scores land
// in SGPRs; per-wave online-softmax state merged across 4 waves via LDS.
__global__ __launch_bounds__(256) void main_pass_kernel(
    const float* __restrict__ hs, const float* __restrict__ v,
    float* __restrict__ M, float* __restrict__ L, float* __restrict__ CTX) {
    const int chunk = blockIdx.x;   // 0..kS-1
    const int b = blockIdx.y;       // 0..kB-1
    const int tid = threadIdx.x;
    const int wv = tid >> 6, lane = tid & 63;

    const float4 vv = *reinterpret_cast<const float4*>(&v[b * kH + lane * 4]);
    const float* base = hs + (size_t)b * kT * kH + (size_t)chunk * kTC * kH;

    float m = -INFINITY, l = 0.f;
    float4 acc = make_float4(0.f, 0.f, 0.f, 0.f);

    for (int it = 0; it < kTC / 32; ++it) {          // 4 iterations
        const float* p = base + (size_t)(it * 32 + wv * 8) * kH + lane * 4;
        float4 x[8];
        #pragma unroll
        for (int j = 0; j < 8; ++j)
            x[j] = *reinterpret_cast<const float4*>(p + j * kH);
        float s[8];
        #pragma unroll
        for (int j = 0; j < 8; ++j) s[j] = wave_sum(dot4(x[j], vv));

        float nm = m;
        #pragma unroll
        for (int j = 0; j < 8; ++j) nm = fmaxf(nm, s[j]);
        const float scale = __expf(m - nm);
        float pj[8], psum = 0.f;
        #pragma unroll
        for (int j = 0; j < 8; ++j) { pj[j] = __expf(s[j] - nm); psum += pj[j]; }
        l = fmaf(l, scale, psum);

        float ix = 0.f, iy = 0.f, iz = 0.f, iw = 0.f;
        #pragma unroll
        for (int j = 0; j < 8; ++j) {
            ix = fmaf(pj[j], x[j].x, ix);
            iy = fmaf(pj[j], x[j].y, iy);
            iz = fmaf(pj[j], x[j].z, iz);
            iw = fmaf(pj[j], x[j].w, iw);
        }
        acc.x = fmaf(acc.x, scale, ix);
        acc.y = fmaf(acc.y, scale, iy);
        acc.z = fmaf(acc.z, scale, iz);
        acc.w = fmaf(acc.w, scale, iw);
        m = nm;
    }

    // Merge the 4 waves' partial softmax states in LDS.
    __shared__ float shm[4];
    __shared__ float shl[4];
    __shared__ float shctx[4 * kH];
    if (lane == 0) { shm[wv] = m; shl[wv] = l; }
    *reinterpret_cast<float4*>(&shctx[wv * kH + lane * 4]) = acc;
    __syncthreads();

    const float m0 = shm[0], m1 = shm[1], m2 = shm[2], m3 = shm[3];
    const float gm = fmaxf(fmaxf(m0, m1), fmaxf(m2, m3));
    const float e0 = __expf(m0 - gm), e1 = __expf(m1 - gm);
    const float e2 = __expf(m2 - gm), e3 = __expf(m3 - gm);

    const int pidx = b * kS + chunk;
    const float ctx = shctx[tid] * e0 + shctx[kH + tid] * e1 +
                      shctx[2 * kH + tid] * e2 + shctx[3 * kH + tid] * e3;
    CTX[(size_t)pidx * kH + tid] = ctx;
    if (tid == 0) {
        M[pidx] = gm;
        L[pidx] = shl[0] * e0 + shl[1] * e1 + shl[2] * e2 + shl[3] * e3;
    }
}

// ---- Kernel C: merge chunk partials, concat with h_t, matvec W_att, tanh ----
__global__ __launch_bounds__(256) void finalize_kernel(
    const float* __restrict__ hs, const float* __restrict__ M,
    const float* __restrict__ L, const float* __restrict__ CTX,
    const float* __restrict__ Watt, float* __restrict__ out) {
    const int b = blockIdx.x;
    const int tid = threadIdx.x;     // 256 threads
    __shared__ float pre[2 * kH];    // [context(256) | h_t(256)]
    __shared__ float red[128];

    float gm = -INFINITY;
    #pragma unroll
    for (int c = 0; c < kS; ++c) gm = fmaxf(gm, M[b * kS + c]);
    float gl = 0.f, ctx = 0.f;
    #pragma unroll
    for (int c = 0; c < kS; ++c) {
        const float e = __expf(M[b * kS + c] - gm);
        gl = fmaf(L[b * kS + c], e, gl);
        ctx = fmaf(CTX[(size_t)(b * kS + c) * kH + tid], e, ctx);
    }
    pre[tid] = ctx / gl;
    pre[kH + tid] = hs[(size_t)b * kT * kH + (size_t)(kT - 1) * kH + tid];
    __syncthreads();

    const int j = tid & 127, half = tid >> 7;
    float s = 0.f;
    const int i0 = half * 256;
    #pragma unroll 4
    for (int i = i0; i < i0 + 256; ++i)
        s = fmaf(pre[i], Watt[(size_t)i * 128 + j], s);
    if (half == 1) red[j] = s;
    __syncthreads();
    if (half == 0) out[b * 128 + j] = tanhf(s + red[j]);
}

extern "C" void kernel_launch(void* const* d_in, const int* in_sizes, int n_in,
                              void* d_out, int out_size, void* d_ws, size_t ws_size,
                              hipStream_t stream) {
    const float* hs   = (const float*)d_in[0];   // (B, T, H) fp32
    const float* Wsc  = (const float*)d_in[1];   // (H, H) fp32
    const float* Watt = (const float*)d_in[2];   // (2H, 128) fp32
    float* out = (float*)d_out;                  // (B, 128) fp32

    float* ws  = (float*)d_ws;
    float* v   = ws;                 // kB*kH        = 32768 floats
    float* M   = v + kB * kH;        // kB*kS        = 2048
    float* L   = M + kB * kS;        // kB*kS        = 2048
    float* CTX = L + kB * kS;        // kB*kS*kH     = 524288 floats

    compute_v_kernel<<<dim3(2, kB), 256, 0, stream>>>(hs, Wsc, v);
    main_pass_kernel<<<dim3(kS, kB), 256, 0, stream>>>(hs, v, M, L, CTX);
    finalize_kernel<<<kB, 256, 0, stream>>>(hs, M, L, CTX, Watt, out);
}

// Round 4
// 364.527 us; speedup vs baseline: 1.1623x; 1.0960x over previous
//
#include <hip/hip_runtime.h>
#include <math.h>

namespace {
constexpr int kB = 128;
constexpr int kT = 2048;
constexpr int kH = 256;
constexpr int kS = 16;            // chunks per batch (main pass)
constexpr int kTC = kT / kS;      // 128 timesteps per workgroup
}

typedef float vfloat4 __attribute__((ext_vector_type(4)));

__device__ __forceinline__ float dot4v(vfloat4 a, const float4& b) {
    return fmaf(a.x, b.x, fmaf(a.y, b.y, fmaf(a.z, b.z, a.w * b.w)));
}

__device__ __forceinline__ vfloat4 nt_load4(const float* p) {
    return __builtin_nontemporal_load(reinterpret_cast<const vfloat4*>(p));
}

// DPP-based full-wave64 sum reduction (no DS ops); result wave-uniform.
template <int CTRL, int ROW_MASK>
__device__ __forceinline__ float dpp_add(float x) {
    int n = __builtin_amdgcn_update_dpp(0, __float_as_int(x), CTRL, ROW_MASK,
                                        0xf, true);
    return x + __int_as_float(n);
}

__device__ __forceinline__ float wave_sum(float x) {
    x = dpp_add<0xB1, 0xf>(x);    // quad_perm xor1
    x = dpp_add<0x4E, 0xf>(x);    // quad_perm xor2
    x = dpp_add<0x141, 0xf>(x);   // row_half_mirror
    x = dpp_add<0x140, 0xf>(x);   // row_mirror
    x = dpp_add<0x142, 0xa>(x);   // row_bcast15
    x = dpp_add<0x143, 0xc>(x);   // row_bcast31
    return __int_as_float(__builtin_amdgcn_readlane(__float_as_int(x), 63));
}

// ---- Kernel A: v[b,h] = sum_k W_score[h,k] * hidden[b,T-1,k] ----
__global__ __launch_bounds__(256) void compute_v_kernel(
    const float* __restrict__ hs, const float* __restrict__ Wsc,
    float* __restrict__ v) {
    const int half = blockIdx.x;     // 0..1
    const int b = blockIdx.y;
    const int tid = threadIdx.x;
    __shared__ float sh[kH];
    sh[tid] = hs[(size_t)b * kT * kH + (size_t)(kT - 1) * kH + tid];
    __syncthreads();
    const int wv = tid >> 6, lane = tid & 63;
    const float4 hv = *reinterpret_cast<const float4*>(&sh[lane * 4]);
    #pragma unroll 4
    for (int r = 0; r < 32; ++r) {
        const int h = half * 128 + wv * 32 + r;
        const vfloat4 wr =
            *reinterpret_cast<const vfloat4*>(&Wsc[(size_t)h * kH + lane * 4]);
        const float s = wave_sum(dot4v(wr, hv));
        if (lane == 0) v[b * kH + h] = s;
    }
}

// ---- Kernel B: fused score + online softmax + weighted context, one pass ----
// 4 timesteps/wave-iteration (VGPR <= 64 -> 8 waves/SIMD -> grid 2048 fits in
// exactly one residency round), DPP reductions, nontemporal streaming loads.
__global__ __launch_bounds__(256, 8) void main_pass_kernel(
    const float* __restrict__ hs, const float* __restrict__ v,
    float* __restrict__ M, float* __restrict__ L, float* __restrict__ CTX) {
    const int chunk = blockIdx.x;   // 0..kS-1
    const int b = blockIdx.y;       // 0..kB-1
    const int tid = threadIdx.x;
    const int wv = tid >> 6, lane = tid & 63;

    const float4 vv = *reinterpret_cast<const float4*>(&v[b * kH + lane * 4]);
    const float* p = hs + (size_t)b * kT * kH + (size_t)chunk * kTC * kH +
                     (size_t)(wv * 4) * kH + lane * 4;

    float m = -INFINITY, l = 0.f;
    float4 acc = make_float4(0.f, 0.f, 0.f, 0.f);

    #pragma unroll 2
    for (int it = 0; it < kTC / 16; ++it) {          // 8 iterations
        const vfloat4 x0 = nt_load4(p);
        const vfloat4 x1 = nt_load4(p + kH);
        const vfloat4 x2 = nt_load4(p + 2 * kH);
        const vfloat4 x3 = nt_load4(p + 3 * kH);
        const float s0 = wave_sum(dot4v(x0, vv));
        const float s1 = wave_sum(dot4v(x1, vv));
        const float s2 = wave_sum(dot4v(x2, vv));
        const float s3 = wave_sum(dot4v(x3, vv));

        const float nm = fmaxf(fmaxf(m, fmaxf(s0, s1)), fmaxf(s2, s3));
        const float scale = __expf(m - nm);
        const float p0 = __expf(s0 - nm);
        const float p1 = __expf(s1 - nm);
        const float p2 = __expf(s2 - nm);
        const float p3 = __expf(s3 - nm);
        l = fmaf(l, scale, (p0 + p1) + (p2 + p3));
        acc.x = fmaf(acc.x, scale,
                     fmaf(p0, x0.x, fmaf(p1, x1.x, fmaf(p2, x2.x, p3 * x3.x))));
        acc.y = fmaf(acc.y, scale,
                     fmaf(p0, x0.y, fmaf(p1, x1.y, fmaf(p2, x2.y, p3 * x3.y))));
        acc.z = fmaf(acc.z, scale,
                     fmaf(p0, x0.z, fmaf(p1, x1.z, fmaf(p2, x2.z, p3 * x3.z))));
        acc.w = fmaf(acc.w, scale,
                     fmaf(p0, x0.w, fmaf(p1, x1.w, fmaf(p2, x2.w, p3 * x3.w))));
        m = nm;
        p += 16 * kH;
    }

    // Merge the 4 waves' partial softmax states in LDS.
    __shared__ float shm[4];
    __shared__ float shl[4];
    __shared__ float shctx[4 * kH];
    if (lane == 0) { shm[wv] = m; shl[wv] = l; }
    *reinterpret_cast<float4*>(&shctx[wv * kH + lane * 4]) = acc;
    __syncthreads();

    const float m0 = shm[0], m1 = shm[1], m2 = shm[2], m3 = shm[3];
    const float gm = fmaxf(fmaxf(m0, m1), fmaxf(m2, m3));
    const float e0 = __expf(m0 - gm), e1 = __expf(m1 - gm);
    const float e2 = __expf(m2 - gm), e3 = __expf(m3 - gm);

    const int pidx = b * kS + chunk;
    const float ctx = shctx[tid] * e0 + shctx[kH + tid] * e1 +
                      shctx[2 * kH + tid] * e2 + shctx[3 * kH + tid] * e3;
    CTX[(size_t)pidx * kH + tid] = ctx;
    if (tid == 0) {
        M[pidx] = gm;
        L[pidx] = shl[0] * e0 + shl[1] * e1 + shl[2] * e2 + shl[3] * e3;
    }
}

// ---- Kernel C: merge chunk partials, concat with h_t, matvec W_att, tanh ----
// grid (2, kB): block computes 64 outputs, i-range split 4-way across waves.
__global__ __launch_bounds__(256) void finalize_kernel(
    const float* __restrict__ hs, const float* __restrict__ M,
    const float* __restrict__ L, const float* __restrict__ CTX,
    const float* __restrict__ Watt, float* __restrict__ out) {
    const int half = blockIdx.x;     // 0..1
    const int b = blockIdx.y;
    const int tid = threadIdx.x;     // 256 threads
    __shared__ float pre[2 * kH];    // [context(256) | h_t(256)]
    __shared__ float red[4][64];

    // Merge kS partials for h = tid (redundant across the 2 blocks; cheap).
    float gm = -INFINITY;
    #pragma unroll
    for (int c = 0; c < kS; ++c) gm = fmaxf(gm, M[b * kS + c]);
    float gl = 0.f, ctx = 0.f;
    #pragma unroll
    for (int c = 0; c < kS; ++c) {
        const float e = __expf(M[b * kS + c] - gm);
        gl = fmaf(L[b * kS + c], e, gl);
        ctx = fmaf(CTX[(size_t)(b * kS + c) * kH + tid], e, ctx);
    }
    pre[tid] = ctx / gl;
    pre[kH + tid] = hs[(size_t)b * kT * kH + (size_t)(kT - 1) * kH + tid];
    __syncthreads();

    // out[b, half*64 + j], i-range [q*128, q*128+128) per thread-quarter q.
    const int j = half * 64 + (tid & 63);
    const int q = tid >> 6;
    float s = 0.f;
    const int i0 = q * 128;
    #pragma unroll 4
    for (int i = i0; i < i0 + 128; ++i)
        s = fmaf(pre[i], Watt[(size_t)i * 128 + j], s);
    red[q][tid & 63] = s;
    __syncthreads();
    if (q == 0)
        out[b * 128 + j] =
            tanhf((red[0][tid] + red[1][tid]) + (red[2][tid] + red[3][tid]));
}

extern "C" void kernel_launch(void* const* d_in, const int* in_sizes, int n_in,
                              void* d_out, int out_size, void* d_ws, size_t ws_size,
                              hipStream_t stream) {
    const float* hs   = (const float*)d_in[0];   // (B, T, H) fp32
    const float* Wsc  = (const float*)d_in[1];   // (H, H) fp32
    const float* Watt = (const float*)d_in[2];   // (2H, 128) fp32
    float* out = (float*)d_out;                  // (B, 128) fp32

    float* ws  = (float*)d_ws;
    float* v   = ws;                 // kB*kH        = 32768 floats
    float* M   = v + kB * kH;        // kB*kS        = 2048
    float* L   = M + kB * kS;        // kB*kS        = 2048
    float* CTX = L + kB * kS;        // kB*kS*kH     = 524288 floats

    compute_v_kernel<<<dim3(2, kB), 256, 0, stream>>>(hs, Wsc, v);
    main_pass_kernel<<<dim3(kS, kB), 256, 0, stream>>>(hs, v, M, L, CTX);
    finalize_kernel<<<dim3(2, kB), 256, 0, stream>>>(hs, M, L, CTX, Watt, out);
}